// Round 11
// baseline (559.138 us; speedup 1.0000x reference)
//
#include <hip/hip_runtime.h>
#include <math.h>

#define NNODES 50000
#define NPAD 50176         // padded rows for unguarded global_load_lds staging
#define FIN 512
#define HID 64
#define HEADS 4
#define HD (HEADS * HID)   // 256
#define NCLS 40
#define NCLSP 48           // padded to 3x16 for MFMA n-tiles
#define NEG_SLOPE 0.2f

typedef __attribute__((ext_vector_type(8))) short short8;
typedef __attribute__((ext_vector_type(4))) float f32x4;

static __device__ inline unsigned short f2bf(float f) {
    unsigned int u = __builtin_bit_cast(unsigned int, f);
    unsigned int r = (u + 0x7FFFu + ((u >> 16) & 1u)) >> 16;
    return (unsigned short)r;
}
static __device__ inline float bf2f(unsigned short b) {
    return __builtin_bit_cast(float, (unsigned int)b << 16);
}
static __device__ inline void gload_lds16(const unsigned short* g, unsigned short* l) {
    __builtin_amdgcn_global_load_lds(
        (const __attribute__((address_space(1))) unsigned int*)g,
        (__attribute__((address_space(3))) unsigned int*)l, 16, 0, 0);
}

// ---------------- x cast: x[50000,512] fp32 -> xb[50176,512] bf16 (pad=0) ----
__global__ __launch_bounds__(256) void xcast_kernel(const float* __restrict__ x,
                                                    unsigned short* __restrict__ xb) {
    const size_t idx = ((size_t)blockIdx.x * 256 + threadIdx.x) * 8;
    if (idx < (size_t)NNODES * FIN) {
        const float4 v0 = *(const float4*)&x[idx];
        const float4 v1 = *(const float4*)&x[idx + 4];
        ushort4 p0, p1;
        p0.x = f2bf(v0.x); p0.y = f2bf(v0.y); p0.z = f2bf(v0.z); p0.w = f2bf(v0.w);
        p1.x = f2bf(v1.x); p1.y = f2bf(v1.y); p1.z = f2bf(v1.z); p1.w = f2bf(v1.w);
        *(ushort4*)&xb[idx] = p0;
        *(ushort4*)&xb[idx + 4] = p1;
    } else {
        const ushort4 z = {0, 0, 0, 0};
        *(ushort4*)&xb[idx] = z;
        *(ushort4*)&xb[idx + 4] = z;
    }
}

// ---------------- W1 cast+transpose: W1[512,256] fp32 -> W1t[256,512] bf16 ---
__global__ __launch_bounds__(256) void w1t_kernel(const float* __restrict__ W1,
                                                  unsigned short* __restrict__ W1t) {
    const int idx = blockIdx.x * 256 + threadIdx.x;
    const int k = idx >> 8;          // 0..511
    const int n = idx & 255;         // 0..255
    W1t[n * FIN + k] = f2bf(W1[idx]);
}

// ---------------- W2 cast+transpose: W2[256,40] fp32 -> W2t[48][256] bf16 ----
__global__ __launch_bounds__(256) void w2t_kernel(const float* __restrict__ W2,
                                                  unsigned short* __restrict__ W2t) {
    const int idx = blockIdx.x * 256 + threadIdx.x;  // 48 blocks
    const int n = idx >> 8;          // 0..47
    const int k = idx & 255;         // 0..255
    W2t[n * HD + k] = (n < NCLS) ? f2bf(W2[k * NCLS + n]) : (unsigned short)0;
}

// ---------------- GEMM1 (m97 pattern): h1 = xb @ W1t^T via global_load_lds ---
#define BM 128
#define BN 128
#define BK 32

__global__ __launch_bounds__(256) void gemm1_kernel(const unsigned short* __restrict__ xb,
                                                    const unsigned short* __restrict__ W1t,
                                                    unsigned short* __restrict__ h1) {
    __shared__ unsigned short As[BM * BK];  // 8 KB, [m][k] unpadded (DMA layout)
    __shared__ unsigned short Bs[BN * BK];  // 8 KB, [n][k]
    const int tid = threadIdx.x;
    const int wave = tid >> 6;
    const int lane = tid & 63;
    const int wm = wave >> 1;
    const int wn = wave & 1;
    const int quad = lane >> 4;
    const int col = lane & 15;
    const int m0 = blockIdx.x * BM;
    const int n0 = blockIdx.y * BN;
    const int srow = wave * 32 + (lane >> 2);
    const int skk = (lane & 3) * 8;

    f32x4 acc[4][4] = {};

    for (int k0 = 0; k0 < FIN; k0 += BK) {
        #pragma unroll
        for (int c = 0; c < 2; ++c) {
            const int r = srow + c * 16;
            gload_lds16(&xb[(size_t)(m0 + r) * FIN + k0 + skk], &As[r * BK + skk]);
            gload_lds16(&W1t[(size_t)(n0 + r) * FIN + k0 + skk], &Bs[r * BK + skk]);
        }
        __syncthreads();

        short8 af[4], bf[4];
        #pragma unroll
        for (int i = 0; i < 4; ++i)
            af[i] = *(const short8*)&As[(wm * 64 + i * 16 + col) * BK + quad * 8];
        #pragma unroll
        for (int j = 0; j < 4; ++j)
            bf[j] = *(const short8*)&Bs[(wn * 64 + j * 16 + col) * BK + quad * 8];
        #pragma unroll
        for (int i = 0; i < 4; ++i)
            #pragma unroll
            for (int j = 0; j < 4; ++j)
                acc[i][j] = __builtin_amdgcn_mfma_f32_16x16x32_bf16(af[i], bf[j], acc[i][j], 0, 0, 0);
        __syncthreads();
    }

    #pragma unroll
    for (int i = 0; i < 4; ++i) {
        #pragma unroll
        for (int reg = 0; reg < 4; ++reg) {
            const int gm = m0 + wm * 64 + i * 16 + quad * 4 + reg;
            if (gm < NNODES) {
                #pragma unroll
                for (int j = 0; j < 4; ++j) {
                    const int gc = n0 + wn * 64 + j * 16 + col;
                    h1[(size_t)gm * HD + gc] = f2bf(acc[i][j][reg]);
                }
            }
        }
    }
}

// ---------------- per-node attention scores for layer 1 ----------------------
__global__ __launch_bounds__(256) void al1_kernel(const unsigned short* __restrict__ h1,
                                                  const float* __restrict__ a_src,
                                                  const float* __restrict__ a_dst,
                                                  float* __restrict__ al_s,
                                                  float* __restrict__ al_d) {
    const int node = (blockIdx.x * 256 + threadIdx.x) >> 6;
    const int lane = threadIdx.x & 63;
    const ushort4 hb = *(const ushort4*)&h1[(size_t)node * HD + lane * 4];
    const float4 sv = *(const float4*)&a_src[lane * 4];
    const float4 dv = *(const float4*)&a_dst[lane * 4];
    const float h0 = bf2f(hb.x), h1v = bf2f(hb.y), h2v = bf2f(hb.z), h3 = bf2f(hb.w);
    float ps = h0 * sv.x + h1v * sv.y + h2v * sv.z + h3 * sv.w;
    float pd = h0 * dv.x + h1v * dv.y + h2v * dv.z + h3 * dv.w;
    #pragma unroll
    for (int off = 1; off < 16; off <<= 1) {
        ps += __shfl_xor(ps, off);
        pd += __shfl_xor(pd, off);
    }
    if ((lane & 15) == 0) {
        al_s[node * HEADS + (lane >> 4)] = ps;
        al_d[node * HEADS + (lane >> 4)] = pd;
    }
}

// ---------------- CSR build --------------------------------------------------
__global__ void deg_kernel(const int* __restrict__ ei, int E, int* __restrict__ deg) {
    const int e = blockIdx.x * 256 + threadIdx.x;
    if (e < E) atomicAdd(&deg[ei[E + e]], 1);
}

__global__ __launch_bounds__(1024) void scan_kernel(const int* __restrict__ deg,
                                                    int* __restrict__ offsets) {
    __shared__ int sums[1024];
    const int t = threadIdx.x;
    const int CH = (NNODES + 1023) / 1024;  // 49
    const int lo = t * CH;
    const int hi = min(lo + CH, NNODES);
    int s = 0;
    for (int i = lo; i < hi; ++i) s += deg[i];
    sums[t] = s;
    __syncthreads();
    for (int off = 1; off < 1024; off <<= 1) {
        int v = 0;
        if (t >= off) v = sums[t - off];
        __syncthreads();
        if (t >= off) sums[t] += v;
        __syncthreads();
    }
    int run = (t > 0) ? sums[t - 1] : 0;
    for (int i = lo; i < hi; ++i) {
        offsets[i] = run;
        run += deg[i];
    }
    if (t == 1023) offsets[NNODES] = sums[1023];
}

__global__ void scatter_kernel(const int* __restrict__ ei, int E,
                               const int* __restrict__ offsets,
                               int* __restrict__ cursor,
                               int* __restrict__ csr_src) {
    const int e = blockIdx.x * 256 + threadIdx.x;
    if (e < E) {
        const int dst = ei[E + e];
        const int src = ei[e];
        const int pos = offsets[dst] + atomicAdd(&cursor[dst], 1);
        csr_src[pos] = src;
    }
}

// ---------------- layer-1 aggregation: 4-slot interleaved prefetch -----------
// Direct exp (no max; scores bounded ~|8| << 87), -inf padding = exact no-op.
// Each slot is processed then immediately refilled -> no register copies,
// ~9-12 loads in flight/wave at steady state.
__global__ __launch_bounds__(256) void agg1_kernel(const unsigned short* __restrict__ h1,
                                                   const float* __restrict__ al_s,
                                                   const float* __restrict__ al_d,
                                                   const int* __restrict__ offsets,
                                                   const int* __restrict__ csr_src,
                                                   const float* __restrict__ b1,
                                                   unsigned short* __restrict__ h_act) {
    const int node = (blockIdx.x * 256 + threadIdx.x) >> 6;
    const int lane = threadIdx.x & 63;
    const int h = lane >> 4;
    const float ad = al_d[node * HEADS + h];
    const int start = offsets[node];
    const int end = offsets[node + 1];
    const int last = end - 1;

    float s0 = 0.f, s1 = 0.f;
    float4 a0 = make_float4(0.f, 0.f, 0.f, 0.f);
    float4 a1 = make_float4(0.f, 0.f, 0.f, 0.f);
    float nsc[4];
    ushort4 nv[4];

    #pragma unroll
    for (int t = 0; t < 4; ++t) {
        const int idx = start + t;
        const int src = csr_src[min(idx, last)];
        nsc[t] = (idx < end) ? al_s[src * HEADS + h] : -__builtin_inff();
        nv[t] = *(const ushort4*)&h1[(size_t)src * HD + lane * 4];
    }

    for (int i = start; i < end; i += 4) {
        #pragma unroll
        for (int t = 0; t < 4; ++t) {
            // process slot t (loaded one group ago)
            float e_ = nsc[t] + ad;
            e_ = e_ > 0.f ? e_ : NEG_SLOPE * e_;
            const float p = __expf(e_);
            const ushort4 v = nv[t];
            // refill slot t for edge i+4+t (issues while remaining slots process)
            const int idx = i + 4 + t;
            const int src = csr_src[min(idx, last)];
            nsc[t] = (idx < end) ? al_s[src * HEADS + h] : -__builtin_inff();
            nv[t] = *(const ushort4*)&h1[(size_t)src * HD + lane * 4];
            if (t & 1) {
                s1 += p;
                a1.x = fmaf(p, bf2f(v.x), a1.x);
                a1.y = fmaf(p, bf2f(v.y), a1.y);
                a1.z = fmaf(p, bf2f(v.z), a1.z);
                a1.w = fmaf(p, bf2f(v.w), a1.w);
            } else {
                s0 += p;
                a0.x = fmaf(p, bf2f(v.x), a0.x);
                a0.y = fmaf(p, bf2f(v.y), a0.y);
                a0.z = fmaf(p, bf2f(v.z), a0.z);
                a0.w = fmaf(p, bf2f(v.w), a0.w);
            }
        }
    }
    const float s = s0 + s1;
    float4 acc;
    acc.x = a0.x + a1.x;
    acc.y = a0.y + a1.y;
    acc.z = a0.z + a1.z;
    acc.w = a0.w + a1.w;

    const float inv = 1.f / (s + 1e-16f);
    const float4 bb = *(const float4*)&b1[lane * 4];
    float4 o;
    o.x = acc.x * inv + bb.x;
    o.y = acc.y * inv + bb.y;
    o.z = acc.z * inv + bb.z;
    o.w = acc.w * inv + bb.w;
    o.x = o.x > 0.f ? o.x : expm1f(o.x);
    o.y = o.y > 0.f ? o.y : expm1f(o.y);
    o.z = o.z > 0.f ? o.z : expm1f(o.z);
    o.w = o.w > 0.f ? o.w : expm1f(o.w);
    ushort4 ob;
    ob.x = f2bf(o.x); ob.y = f2bf(o.y); ob.z = f2bf(o.z); ob.w = f2bf(o.w);
    *(ushort4*)&h_act[(size_t)node * HD + lane * 4] = ob;
}

// ---------------- GEMM2 via MFMA: h2[N,40] = h_act[N,256] @ W2 + score dots --
#define G2M 64          // nodes per block (16 per wave)
#define BSTRIDE 264

__global__ __launch_bounds__(256) void gemm2_kernel(const unsigned short* __restrict__ h_act,
                                                    const unsigned short* __restrict__ W2t,
                                                    const float* __restrict__ a_s2,
                                                    const float* __restrict__ a_d2,
                                                    unsigned short* __restrict__ h2,
                                                    float* __restrict__ al_s,
                                                    float* __restrict__ al_d) {
    __shared__ unsigned short Bt[NCLSP][BSTRIDE];  // 25.3 KB
    const int tid = threadIdx.x;
    const int wave = tid >> 6;
    const int lane = tid & 63;
    const int quad = lane >> 4;
    const int col = lane & 15;
    const int m0 = blockIdx.x * G2M;

    #pragma unroll
    for (int it = 0; it < 6; ++it) {
        const int ch = it * 256 + tid;        // 0..1535
        const int n = ch >> 5;
        const int c8 = (ch & 31) * 8;
        *(uint4*)&Bt[n][c8] = *(const uint4*)&W2t[(size_t)n * HD + c8];
    }

    const int rowm = m0 + wave * 16 + col;
    const int arow = min(rowm, NNODES - 1);
    short8 af[8];
    #pragma unroll
    for (int ks = 0; ks < 8; ++ks)
        af[ks] = *(const short8*)&h_act[(size_t)arow * HD + ks * 32 + quad * 8];

    __syncthreads();

    f32x4 acc[3] = {};
    #pragma unroll
    for (int j = 0; j < 3; ++j) {
        #pragma unroll
        for (int ks = 0; ks < 8; ++ks) {
            const short8 bfr = *(const short8*)&Bt[j * 16 + col][ks * 32 + quad * 8];
            acc[j] = __builtin_amdgcn_mfma_f32_16x16x32_bf16(af[ks], bfr, acc[j], 0, 0, 0);
        }
    }

    float ps[4] = {0.f, 0.f, 0.f, 0.f};
    float pd[4] = {0.f, 0.f, 0.f, 0.f};
    #pragma unroll
    for (int j = 0; j < 3; ++j) {
        const int c = j * 16 + col;
        const bool cv = c < NCLS;
        const float asc = cv ? a_s2[c] : 0.f;
        const float adc = cv ? a_d2[c] : 0.f;
        #pragma unroll
        for (int reg = 0; reg < 4; ++reg) {
            const float v = acc[j][reg];
            ps[reg] += v * asc;
            pd[reg] += v * adc;
            const int node = m0 + wave * 16 + quad * 4 + reg;
            if (cv && node < NNODES)
                h2[(size_t)node * NCLS + c] = f2bf(v);
        }
    }
    #pragma unroll
    for (int reg = 0; reg < 4; ++reg) {
        #pragma unroll
        for (int off = 1; off < 16; off <<= 1) {
            ps[reg] += __shfl_xor(ps[reg], off);
            pd[reg] += __shfl_xor(pd[reg], off);
        }
    }
    if (col == 0) {
        #pragma unroll
        for (int reg = 0; reg < 4; ++reg) {
            const int node = m0 + wave * 16 + quad * 4 + reg;
            if (node < NNODES) {
                al_s[node] = ps[reg];
                al_d[node] = pd[reg];
            }
        }
    }
}

// ---------------- layer-2 aggregation: 4-slot interleaved + log_softmax ------
__global__ __launch_bounds__(256) void agg2_kernel(const unsigned short* __restrict__ h2,
                                                   const float* __restrict__ al_s,
                                                   const float* __restrict__ al_d,
                                                   const int* __restrict__ offsets,
                                                   const int* __restrict__ csr_src,
                                                   const float* __restrict__ b2,
                                                   float* __restrict__ out) {
    const int node = (blockIdx.x * 256 + threadIdx.x) >> 6;
    const int lane = threadIdx.x & 63;
    const int c = lane < NCLS ? lane : NCLS - 1;
    const float ad = al_d[node];
    const int start = offsets[node];
    const int end = offsets[node + 1];
    const int last = end - 1;

    float s0 = 0.f, s1 = 0.f, a0 = 0.f, a1 = 0.f;
    float nsc[4], nv[4];

    #pragma unroll
    for (int t = 0; t < 4; ++t) {
        const int idx = start + t;
        const int src = csr_src[min(idx, last)];
        nsc[t] = (idx < end) ? al_s[src] : -__builtin_inff();
        nv[t] = bf2f(h2[(size_t)src * NCLS + c]);
    }

    for (int i = start; i < end; i += 4) {
        #pragma unroll
        for (int t = 0; t < 4; ++t) {
            float e_ = nsc[t] + ad;
            e_ = e_ > 0.f ? e_ : NEG_SLOPE * e_;
            const float p = __expf(e_);
            const float v = nv[t];
            const int idx = i + 4 + t;
            const int src = csr_src[min(idx, last)];
            nsc[t] = (idx < end) ? al_s[src] : -__builtin_inff();
            nv[t] = bf2f(h2[(size_t)src * NCLS + c]);
            if (t & 1) { s1 += p; a1 = fmaf(p, v, a1); }
            else       { s0 += p; a0 = fmaf(p, v, a0); }
        }
    }
    const float s = s0 + s1;
    const float acc = a0 + a1;

    float o = acc / (s + 1e-16f) + b2[c];
    float mx = (lane < NCLS) ? o : -1e30f;
    #pragma unroll
    for (int off = 1; off < 64; off <<= 1) mx = fmaxf(mx, __shfl_xor(mx, off));
    float ex = (lane < NCLS) ? __expf(o - mx) : 0.f;
    #pragma unroll
    for (int off = 1; off < 64; off <<= 1) ex += __shfl_xor(ex, off);
    const float res = o - mx - logf(ex);
    if (lane < NCLS) out[(size_t)node * NCLS + lane] = res;
}

// ---------------- launch -----------------------------------------------------
extern "C" void kernel_launch(void* const* d_in, const int* in_sizes, int n_in,
                              void* d_out, int out_size, void* d_ws, size_t ws_size,
                              hipStream_t stream) {
    const float* x      = (const float*)d_in[0];
    const int*   ei     = (const int*)d_in[1];
    const float* W1     = (const float*)d_in[2];
    const float* a_src1 = (const float*)d_in[3];
    const float* a_dst1 = (const float*)d_in[4];
    const float* b1     = (const float*)d_in[5];
    const float* W2     = (const float*)d_in[6];
    const float* a_src2 = (const float*)d_in[7];
    const float* a_dst2 = (const float*)d_in[8];
    const float* b2     = (const float*)d_in[9];
    float* out = (float*)d_out;
    const int E = in_sizes[1] / 2;

    char* ws = (char*)d_ws;
    size_t off = 0;
    auto alloc = [&](size_t bytes) -> char* {
        char* p = ws + off;
        off += (bytes + 255) & ~(size_t)255;
        return p;
    };
    unsigned short* xb    = (unsigned short*)alloc((size_t)NPAD * FIN * 2);
    unsigned short* W1t   = (unsigned short*)alloc((size_t)FIN * HD * 2);
    unsigned short* W2t   = (unsigned short*)alloc((size_t)NCLSP * HD * 2);
    unsigned short* h1    = (unsigned short*)alloc((size_t)NNODES * HD * 2);
    unsigned short* h_act = (unsigned short*)alloc((size_t)NNODES * HD * 2);
    unsigned short* h2    = (unsigned short*)alloc((size_t)NNODES * NCLS * 2);
    float* al_s1  = (float*)alloc((size_t)NNODES * HEADS * 4);
    float* al_d1  = (float*)alloc((size_t)NNODES * HEADS * 4);
    float* al_s2  = (float*)alloc((size_t)NNODES * 4);
    float* al_d2  = (float*)alloc((size_t)NNODES * 4);
    int*   deg    = (int*)alloc((size_t)NNODES * 4);
    int*   offs   = (int*)alloc((size_t)(NNODES + 1) * 4);
    int*   cursor = (int*)alloc((size_t)NNODES * 4);
    int*   csrsrc = (int*)alloc((size_t)E * 4);

    hipMemsetAsync(deg, 0, (size_t)NNODES * 4, stream);
    hipMemsetAsync(cursor, 0, (size_t)NNODES * 4, stream);

    const int eb = (E + 255) / 256;
    xcast_kernel<<<(int)((size_t)NPAD * FIN / 8 / 256), 256, 0, stream>>>(x, xb);
    w1t_kernel<<<FIN * HD / 256, 256, 0, stream>>>(W1, W1t);
    w2t_kernel<<<NCLSP, 256, 0, stream>>>(W2, W2t);
    deg_kernel<<<eb, 256, 0, stream>>>(ei, E, deg);
    scan_kernel<<<1, 1024, 0, stream>>>(deg, offs);
    scatter_kernel<<<eb, 256, 0, stream>>>(ei, E, offs, cursor, csrsrc);

    gemm1_kernel<<<dim3((NNODES + BM - 1) / BM, HD / BN), 256, 0, stream>>>(xb, W1t, h1);
    al1_kernel<<<NNODES / 4, 256, 0, stream>>>(h1, a_src1, a_dst1, al_s1, al_d1);
    agg1_kernel<<<NNODES / 4, 256, 0, stream>>>(h1, al_s1, al_d1, offs, csrsrc, b1, h_act);
    gemm2_kernel<<<(NNODES + G2M - 1) / G2M, 256, 0, stream>>>(h_act, W2t, a_src2, a_dst2, h2, al_s2, al_d2);
    agg2_kernel<<<NNODES / 4, 256, 0, stream>>>(h2, al_s2, al_d2, offs, csrsrc, b2, out);
}

// Round 12
// 519.556 us; speedup vs baseline: 1.0762x; 1.0762x over previous
//
#include <hip/hip_runtime.h>
#include <math.h>

#define NNODES 50000
#define NPAD 50176         // padded rows for unguarded global_load_lds staging
#define FIN 512
#define HID 64
#define HEADS 4
#define HD (HEADS * HID)   // 256
#define NCLS 40
#define NCLSP 48           // padded to 3x16 for MFMA n-tiles
#define NEG_SLOPE 0.2f

typedef __attribute__((ext_vector_type(8))) short short8;
typedef __attribute__((ext_vector_type(4))) float f32x4;

static __device__ inline unsigned short f2bf(float f) {
    unsigned int u = __builtin_bit_cast(unsigned int, f);
    unsigned int r = (u + 0x7FFFu + ((u >> 16) & 1u)) >> 16;
    return (unsigned short)r;
}
static __device__ inline float bf2f(unsigned short b) {
    return __builtin_bit_cast(float, (unsigned int)b << 16);
}
static __device__ inline void gload_lds16(const unsigned short* g, unsigned short* l) {
    __builtin_amdgcn_global_load_lds(
        (const __attribute__((address_space(1))) unsigned int*)g,
        (__attribute__((address_space(3))) unsigned int*)l, 16, 0, 0);
}

// ---------------- x cast: x[50000,512] fp32 -> xb[50176,512] bf16 (pad=0) ----
__global__ __launch_bounds__(256) void xcast_kernel(const float* __restrict__ x,
                                                    unsigned short* __restrict__ xb) {
    const size_t idx = ((size_t)blockIdx.x * 256 + threadIdx.x) * 8;
    if (idx < (size_t)NNODES * FIN) {
        const float4 v0 = *(const float4*)&x[idx];
        const float4 v1 = *(const float4*)&x[idx + 4];
        ushort4 p0, p1;
        p0.x = f2bf(v0.x); p0.y = f2bf(v0.y); p0.z = f2bf(v0.z); p0.w = f2bf(v0.w);
        p1.x = f2bf(v1.x); p1.y = f2bf(v1.y); p1.z = f2bf(v1.z); p1.w = f2bf(v1.w);
        *(ushort4*)&xb[idx] = p0;
        *(ushort4*)&xb[idx + 4] = p1;
    } else {
        const ushort4 z = {0, 0, 0, 0};
        *(ushort4*)&xb[idx] = z;
        *(ushort4*)&xb[idx + 4] = z;
    }
}

// ---------------- W1 cast+transpose: W1[512,256] fp32 -> W1t[256,512] bf16 ---
__global__ __launch_bounds__(256) void w1t_kernel(const float* __restrict__ W1,
                                                  unsigned short* __restrict__ W1t) {
    const int idx = blockIdx.x * 256 + threadIdx.x;
    const int k = idx >> 8;          // 0..511
    const int n = idx & 255;         // 0..255
    W1t[n * FIN + k] = f2bf(W1[idx]);
}

// ---------------- W2 cast+transpose: W2[256,40] fp32 -> W2t[48][256] bf16 ----
__global__ __launch_bounds__(256) void w2t_kernel(const float* __restrict__ W2,
                                                  unsigned short* __restrict__ W2t) {
    const int idx = blockIdx.x * 256 + threadIdx.x;  // 48 blocks
    const int n = idx >> 8;          // 0..47
    const int k = idx & 255;         // 0..255
    W2t[n * HD + k] = (n < NCLS) ? f2bf(W2[k * NCLS + n]) : (unsigned short)0;
}

// ---------------- GEMM1 (m97 pattern): h1 = xb @ W1t^T via global_load_lds ---
#define BM 128
#define BN 128
#define BK 32

__global__ __launch_bounds__(256) void gemm1_kernel(const unsigned short* __restrict__ xb,
                                                    const unsigned short* __restrict__ W1t,
                                                    unsigned short* __restrict__ h1) {
    __shared__ unsigned short As[BM * BK];  // 8 KB, [m][k] unpadded (DMA layout)
    __shared__ unsigned short Bs[BN * BK];  // 8 KB, [n][k]
    const int tid = threadIdx.x;
    const int wave = tid >> 6;
    const int lane = tid & 63;
    const int wm = wave >> 1;
    const int wn = wave & 1;
    const int quad = lane >> 4;
    const int col = lane & 15;
    const int m0 = blockIdx.x * BM;
    const int n0 = blockIdx.y * BN;
    const int srow = wave * 32 + (lane >> 2);
    const int skk = (lane & 3) * 8;

    f32x4 acc[4][4] = {};

    for (int k0 = 0; k0 < FIN; k0 += BK) {
        #pragma unroll
        for (int c = 0; c < 2; ++c) {
            const int r = srow + c * 16;
            gload_lds16(&xb[(size_t)(m0 + r) * FIN + k0 + skk], &As[r * BK + skk]);
            gload_lds16(&W1t[(size_t)(n0 + r) * FIN + k0 + skk], &Bs[r * BK + skk]);
        }
        __syncthreads();

        short8 af[4], bf[4];
        #pragma unroll
        for (int i = 0; i < 4; ++i)
            af[i] = *(const short8*)&As[(wm * 64 + i * 16 + col) * BK + quad * 8];
        #pragma unroll
        for (int j = 0; j < 4; ++j)
            bf[j] = *(const short8*)&Bs[(wn * 64 + j * 16 + col) * BK + quad * 8];
        #pragma unroll
        for (int i = 0; i < 4; ++i)
            #pragma unroll
            for (int j = 0; j < 4; ++j)
                acc[i][j] = __builtin_amdgcn_mfma_f32_16x16x32_bf16(af[i], bf[j], acc[i][j], 0, 0, 0);
        __syncthreads();
    }

    #pragma unroll
    for (int i = 0; i < 4; ++i) {
        #pragma unroll
        for (int reg = 0; reg < 4; ++reg) {
            const int gm = m0 + wm * 64 + i * 16 + quad * 4 + reg;
            if (gm < NNODES) {
                #pragma unroll
                for (int j = 0; j < 4; ++j) {
                    const int gc = n0 + wn * 64 + j * 16 + col;
                    h1[(size_t)gm * HD + gc] = f2bf(acc[i][j][reg]);
                }
            }
        }
    }
}

// ---------------- per-node attention scores for layer 1 ----------------------
__global__ __launch_bounds__(256) void al1_kernel(const unsigned short* __restrict__ h1,
                                                  const float* __restrict__ a_src,
                                                  const float* __restrict__ a_dst,
                                                  float* __restrict__ al_s,
                                                  float* __restrict__ al_d) {
    const int node = (blockIdx.x * 256 + threadIdx.x) >> 6;
    const int lane = threadIdx.x & 63;
    const ushort4 hb = *(const ushort4*)&h1[(size_t)node * HD + lane * 4];
    const float4 sv = *(const float4*)&a_src[lane * 4];
    const float4 dv = *(const float4*)&a_dst[lane * 4];
    const float h0 = bf2f(hb.x), h1v = bf2f(hb.y), h2v = bf2f(hb.z), h3 = bf2f(hb.w);
    float ps = h0 * sv.x + h1v * sv.y + h2v * sv.z + h3 * sv.w;
    float pd = h0 * dv.x + h1v * dv.y + h2v * dv.z + h3 * dv.w;
    #pragma unroll
    for (int off = 1; off < 16; off <<= 1) {
        ps += __shfl_xor(ps, off);
        pd += __shfl_xor(pd, off);
    }
    if ((lane & 15) == 0) {
        al_s[node * HEADS + (lane >> 4)] = ps;
        al_d[node * HEADS + (lane >> 4)] = pd;
    }
}

// ---------------- CSR build --------------------------------------------------
__global__ void deg_kernel(const int* __restrict__ ei, int E, int* __restrict__ deg) {
    const int e = blockIdx.x * 256 + threadIdx.x;
    if (e < E) atomicAdd(&deg[ei[E + e]], 1);
}

__global__ __launch_bounds__(1024) void scan_kernel(const int* __restrict__ deg,
                                                    int* __restrict__ offsets) {
    __shared__ int sums[1024];
    const int t = threadIdx.x;
    const int CH = (NNODES + 1023) / 1024;  // 49
    const int lo = t * CH;
    const int hi = min(lo + CH, NNODES);
    int s = 0;
    for (int i = lo; i < hi; ++i) s += deg[i];
    sums[t] = s;
    __syncthreads();
    for (int off = 1; off < 1024; off <<= 1) {
        int v = 0;
        if (t >= off) v = sums[t - off];
        __syncthreads();
        if (t >= off) sums[t] += v;
        __syncthreads();
    }
    int run = (t > 0) ? sums[t - 1] : 0;
    for (int i = lo; i < hi; ++i) {
        offsets[i] = run;
        run += deg[i];
    }
    if (t == 1023) offsets[NNODES] = sums[1023];
}

__global__ void scatter_kernel(const int* __restrict__ ei, int E,
                               const int* __restrict__ offsets,
                               int* __restrict__ cursor,
                               int* __restrict__ csr_src) {
    const int e = blockIdx.x * 256 + threadIdx.x;
    if (e < E) {
        const int dst = ei[E + e];
        const int src = ei[e];
        const int pos = offsets[dst] + atomicAdd(&cursor[dst], 1);
        csr_src[pos] = src;
    }
}

// ---------------- layer-1 aggregation: half-wave-per-edge, dual-stream -------
// Lane = (half, fl): half-wave 0 processes edge i, half-wave 1 edge i+1.
// Each lane loads a 16B ushort8 chunk (32 lanes x 16B = full 512B row) -> row
// load instructions per edge-pair halve vs 8B/lane; exp/score VALU per edge
// halves. Direct exp (scores bounded ~|8|), -inf padding = exact no-op.
// Halves merged at the end via shfl_xor(32).
__global__ __launch_bounds__(256) void agg1_kernel(const unsigned short* __restrict__ h1,
                                                   const float* __restrict__ al_s,
                                                   const float* __restrict__ al_d,
                                                   const int* __restrict__ offsets,
                                                   const int* __restrict__ csr_src,
                                                   const float* __restrict__ b1,
                                                   unsigned short* __restrict__ h_act) {
    const int node = (blockIdx.x * 256 + threadIdx.x) >> 6;
    const int lane = threadIdx.x & 63;
    const int half = lane >> 5;
    const int fl = lane & 31;        // 16B chunk index (8 bf16 features)
    const int h = fl >> 3;           // head for features fl*8..fl*8+7
    const float ad = al_d[node * HEADS + h];
    const int start = offsets[node];
    const int end = offsets[node + 1];   // >= start+1 (self-loop)
    const int last = end - 1;

    float s = 0.f;
    float acc[8] = {};

    // prologue: this half's first edge
    {
        const int idx = start + half;
        const int src = csr_src[min(idx, last)];
        float sc = (idx < end) ? al_s[src * HEADS + h] : -__builtin_inff();
        short8 v = *(const short8*)&h1[(size_t)src * HD + fl * 8];

        for (int i = start; i < end; i += 2) {
            const int j = i + 2 + half;
            const int nsrc = csr_src[min(j, last)];
            const float nsc = (j < end) ? al_s[nsrc * HEADS + h] : -__builtin_inff();
            const short8 nv = *(const short8*)&h1[(size_t)nsrc * HD + fl * 8];
            float e_ = sc + ad;
            e_ = e_ > 0.f ? e_ : NEG_SLOPE * e_;
            const float p = __expf(e_);
            s += p;
            #pragma unroll
            for (int k = 0; k < 8; ++k)
                acc[k] = fmaf(p, bf2f((unsigned short)v[k]), acc[k]);
            sc = nsc; v = nv;
        }
    }
    // merge the two halves (each lane pair (fl, fl+32) holds the same chunk)
    s += __shfl_xor(s, 32);
    #pragma unroll
    for (int k = 0; k < 8; ++k) acc[k] += __shfl_xor(acc[k], 32);

    if (half == 0) {
        const float inv = 1.f / (s + 1e-16f);
        const float4 b0 = *(const float4*)&b1[fl * 8];
        const float4 b4 = *(const float4*)&b1[fl * 8 + 4];
        float o[8];
        o[0] = acc[0] * inv + b0.x; o[1] = acc[1] * inv + b0.y;
        o[2] = acc[2] * inv + b0.z; o[3] = acc[3] * inv + b0.w;
        o[4] = acc[4] * inv + b4.x; o[5] = acc[5] * inv + b4.y;
        o[6] = acc[6] * inv + b4.z; o[7] = acc[7] * inv + b4.w;
        short8 ob;
        #pragma unroll
        for (int k = 0; k < 8; ++k) {
            const float e = o[k] > 0.f ? o[k] : expm1f(o[k]);
            ob[k] = (short)f2bf(e);
        }
        *(short8*)&h_act[(size_t)node * HD + fl * 8] = ob;
    }
}

// ---------------- GEMM2 via MFMA: h2[N,40] = h_act[N,256] @ W2 + score dots --
#define G2M 64          // nodes per block (16 per wave)
#define BSTRIDE 264

__global__ __launch_bounds__(256) void gemm2_kernel(const unsigned short* __restrict__ h_act,
                                                    const unsigned short* __restrict__ W2t,
                                                    const float* __restrict__ a_s2,
                                                    const float* __restrict__ a_d2,
                                                    unsigned short* __restrict__ h2,
                                                    float* __restrict__ al_s,
                                                    float* __restrict__ al_d) {
    __shared__ unsigned short Bt[NCLSP][BSTRIDE];  // 25.3 KB
    const int tid = threadIdx.x;
    const int wave = tid >> 6;
    const int lane = tid & 63;
    const int quad = lane >> 4;
    const int col = lane & 15;
    const int m0 = blockIdx.x * G2M;

    #pragma unroll
    for (int it = 0; it < 6; ++it) {
        const int ch = it * 256 + tid;        // 0..1535
        const int n = ch >> 5;
        const int c8 = (ch & 31) * 8;
        *(uint4*)&Bt[n][c8] = *(const uint4*)&W2t[(size_t)n * HD + c8];
    }

    const int rowm = m0 + wave * 16 + col;
    const int arow = min(rowm, NNODES - 1);
    short8 af[8];
    #pragma unroll
    for (int ks = 0; ks < 8; ++ks)
        af[ks] = *(const short8*)&h_act[(size_t)arow * HD + ks * 32 + quad * 8];

    __syncthreads();

    f32x4 acc[3] = {};
    #pragma unroll
    for (int j = 0; j < 3; ++j) {
        #pragma unroll
        for (int ks = 0; ks < 8; ++ks) {
            const short8 bfr = *(const short8*)&Bt[j * 16 + col][ks * 32 + quad * 8];
            acc[j] = __builtin_amdgcn_mfma_f32_16x16x32_bf16(af[ks], bfr, acc[j], 0, 0, 0);
        }
    }

    float ps[4] = {0.f, 0.f, 0.f, 0.f};
    float pd[4] = {0.f, 0.f, 0.f, 0.f};
    #pragma unroll
    for (int j = 0; j < 3; ++j) {
        const int c = j * 16 + col;
        const bool cv = c < NCLS;
        const float asc = cv ? a_s2[c] : 0.f;
        const float adc = cv ? a_d2[c] : 0.f;
        #pragma unroll
        for (int reg = 0; reg < 4; ++reg) {
            const float v = acc[j][reg];
            ps[reg] += v * asc;
            pd[reg] += v * adc;
            const int node = m0 + wave * 16 + quad * 4 + reg;
            if (cv && node < NNODES)
                h2[(size_t)node * NCLS + c] = f2bf(v);
        }
    }
    #pragma unroll
    for (int reg = 0; reg < 4; ++reg) {
        #pragma unroll
        for (int off = 1; off < 16; off <<= 1) {
            ps[reg] += __shfl_xor(ps[reg], off);
            pd[reg] += __shfl_xor(pd[reg], off);
        }
    }
    if (col == 0) {
        #pragma unroll
        for (int reg = 0; reg < 4; ++reg) {
            const int node = m0 + wave * 16 + quad * 4 + reg;
            if (node < NNODES) {
                al_s[node] = ps[reg];
                al_d[node] = pd[reg];
            }
        }
    }
}

// ---------------- layer-2 aggregation: dual-stream, direct exp + log_softmax -
// (R10 measured-best form)
__global__ __launch_bounds__(256) void agg2_kernel(const unsigned short* __restrict__ h2,
                                                   const float* __restrict__ al_s,
                                                   const float* __restrict__ al_d,
                                                   const int* __restrict__ offsets,
                                                   const int* __restrict__ csr_src,
                                                   const float* __restrict__ b2,
                                                   float* __restrict__ out) {
    const int node = (blockIdx.x * 256 + threadIdx.x) >> 6;
    const int lane = threadIdx.x & 63;
    const int c = lane < NCLS ? lane : NCLS - 1;
    const float ad = al_d[node];
    const int start = offsets[node];
    const int end = offsets[node + 1];
    const int last = end - 1;

    float sA = 0.f, sB = 0.f, aA = 0.f, aB = 0.f;

#define PROC2(sc_, v_, s_, a_)                            \
    {                                                     \
        float e_ = sc_ + ad;                              \
        e_ = e_ > 0.f ? e_ : NEG_SLOPE * e_;              \
        const float p_ = __expf(e_);                      \
        s_ += p_;                                         \
        a_ = fmaf(p_, v_, a_);                            \
    }

    int srcA = csr_src[start];
    int srcB = csr_src[min(start + 1, last)];
    float scA = al_s[srcA];
    float scB = (start + 1 < end) ? al_s[srcB] : -__builtin_inff();
    float vA = bf2f(h2[(size_t)srcA * NCLS + c]);
    float vB = bf2f(h2[(size_t)srcB * NCLS + c]);

    for (int i = start; i < end; i += 2) {
        const int j = i + 2;
        const int nsrcA = csr_src[min(j, last)];
        const int nsrcB = csr_src[min(j + 1, last)];
        const float nscA = (j < end) ? al_s[nsrcA] : -__builtin_inff();
        const float nscB = (j + 1 < end) ? al_s[nsrcB] : -__builtin_inff();
        const float nvA = bf2f(h2[(size_t)nsrcA * NCLS + c]);
        const float nvB = bf2f(h2[(size_t)nsrcB * NCLS + c]);
        PROC2(scA, vA, sA, aA);
        PROC2(scB, vB, sB, aB);
        scA = nscA; vA = nvA; scB = nscB; vB = nvB;
    }
    const float s = sA + sB;
    const float acc = aA + aB;
#undef PROC2

    float o = acc / (s + 1e-16f) + b2[c];
    float mx = (lane < NCLS) ? o : -1e30f;
    #pragma unroll
    for (int off = 1; off < 64; off <<= 1) mx = fmaxf(mx, __shfl_xor(mx, off));
    float ex = (lane < NCLS) ? __expf(o - mx) : 0.f;
    #pragma unroll
    for (int off = 1; off < 64; off <<= 1) ex += __shfl_xor(ex, off);
    const float res = o - mx - logf(ex);
    if (lane < NCLS) out[(size_t)node * NCLS + lane] = res;
}

// ---------------- launch -----------------------------------------------------
extern "C" void kernel_launch(void* const* d_in, const int* in_sizes, int n_in,
                              void* d_out, int out_size, void* d_ws, size_t ws_size,
                              hipStream_t stream) {
    const float* x      = (const float*)d_in[0];
    const int*   ei     = (const int*)d_in[1];
    const float* W1     = (const float*)d_in[2];
    const float* a_src1 = (const float*)d_in[3];
    const float* a_dst1 = (const float*)d_in[4];
    const float* b1     = (const float*)d_in[5];
    const float* W2     = (const float*)d_in[6];
    const float* a_src2 = (const float*)d_in[7];
    const float* a_dst2 = (const float*)d_in[8];
    const float* b2     = (const float*)d_in[9];
    float* out = (float*)d_out;
    const int E = in_sizes[1] / 2;

    char* ws = (char*)d_ws;
    size_t off = 0;
    auto alloc = [&](size_t bytes) -> char* {
        char* p = ws + off;
        off += (bytes + 255) & ~(size_t)255;
        return p;
    };
    unsigned short* xb    = (unsigned short*)alloc((size_t)NPAD * FIN * 2);
    unsigned short* W1t   = (unsigned short*)alloc((size_t)FIN * HD * 2);
    unsigned short* W2t   = (unsigned short*)alloc((size_t)NCLSP * HD * 2);
    unsigned short* h1    = (unsigned short*)alloc((size_t)NNODES * HD * 2);
    unsigned short* h_act = (unsigned short*)alloc((size_t)NNODES * HD * 2);
    unsigned short* h2    = (unsigned short*)alloc((size_t)NNODES * NCLS * 2);
    float* al_s1  = (float*)alloc((size_t)NNODES * HEADS * 4);
    float* al_d1  = (float*)alloc((size_t)NNODES * HEADS * 4);
    float* al_s2  = (float*)alloc((size_t)NNODES * 4);
    float* al_d2  = (float*)alloc((size_t)NNODES * 4);
    int*   deg    = (int*)alloc((size_t)NNODES * 4);
    int*   offs   = (int*)alloc((size_t)(NNODES + 1) * 4);
    int*   cursor = (int*)alloc((size_t)NNODES * 4);
    int*   csrsrc = (int*)alloc((size_t)E * 4);

    hipMemsetAsync(deg, 0, (size_t)NNODES * 4, stream);
    hipMemsetAsync(cursor, 0, (size_t)NNODES * 4, stream);

    const int eb = (E + 255) / 256;
    xcast_kernel<<<(int)((size_t)NPAD * FIN / 8 / 256), 256, 0, stream>>>(x, xb);
    w1t_kernel<<<FIN * HD / 256, 256, 0, stream>>>(W1, W1t);
    w2t_kernel<<<NCLSP, 256, 0, stream>>>(W2, W2t);
    deg_kernel<<<eb, 256, 0, stream>>>(ei, E, deg);
    scan_kernel<<<1, 1024, 0, stream>>>(deg, offs);
    scatter_kernel<<<eb, 256, 0, stream>>>(ei, E, offs, cursor, csrsrc);

    gemm1_kernel<<<dim3((NNODES + BM - 1) / BM, HD / BN), 256, 0, stream>>>(xb, W1t, h1);
    al1_kernel<<<NNODES / 4, 256, 0, stream>>>(h1, a_src1, a_dst1, al_s1, al_d1);
    agg1_kernel<<<NNODES / 4, 256, 0, stream>>>(h1, al_s1, al_d1, offs, csrsrc, b1, h_act);
    gemm2_kernel<<<(NNODES + G2M - 1) / G2M, 256, 0, stream>>>(h_act, W2t, a_src2, a_dst2, h2, al_s2, al_d2);
    agg2_kernel<<<NNODES / 4, 256, 0, stream>>>(h2, al_s2, al_d2, offs, csrsrc, b2, out);
}

// Round 13
// 450.366 us; speedup vs baseline: 1.2415x; 1.1536x over previous
//
#include <hip/hip_runtime.h>
#include <math.h>

#define NNODES 50000
#define NPAD 50176         // padded rows for unguarded global_load_lds staging
#define FIN 512
#define HID 64
#define HEADS 4
#define HD (HEADS * HID)   // 256
#define NCLS 40
#define NCLSP 48           // padded to 3x16 for MFMA n-tiles
#define NEG_SLOPE 0.2f
#define SBLK 256
#define NSCAN ((NNODES + SBLK - 1) / SBLK)   // 196

typedef __attribute__((ext_vector_type(8))) short short8;
typedef __attribute__((ext_vector_type(4))) float f32x4;

static __device__ inline unsigned short f2bf(float f) {
    unsigned int u = __builtin_bit_cast(unsigned int, f);
    unsigned int r = (u + 0x7FFFu + ((u >> 16) & 1u)) >> 16;
    return (unsigned short)r;
}
static __device__ inline float bf2f(unsigned short b) {
    return __builtin_bit_cast(float, (unsigned int)b << 16);
}
static __device__ inline void gload_lds16(const unsigned short* g, unsigned short* l) {
    __builtin_amdgcn_global_load_lds(
        (const __attribute__((address_space(1))) unsigned int*)g,
        (__attribute__((address_space(3))) unsigned int*)l, 16, 0, 0);
}

// ---------------- x cast: x[50000,512] fp32 -> xb[50176,512] bf16 (pad=0) ----
__global__ __launch_bounds__(256) void xcast_kernel(const float* __restrict__ x,
                                                    unsigned short* __restrict__ xb) {
    const size_t idx = ((size_t)blockIdx.x * 256 + threadIdx.x) * 8;
    if (idx < (size_t)NNODES * FIN) {
        const float4 v0 = *(const float4*)&x[idx];
        const float4 v1 = *(const float4*)&x[idx + 4];
        ushort4 p0, p1;
        p0.x = f2bf(v0.x); p0.y = f2bf(v0.y); p0.z = f2bf(v0.z); p0.w = f2bf(v0.w);
        p1.x = f2bf(v1.x); p1.y = f2bf(v1.y); p1.z = f2bf(v1.z); p1.w = f2bf(v1.w);
        *(ushort4*)&xb[idx] = p0;
        *(ushort4*)&xb[idx + 4] = p1;
    } else {
        const ushort4 z = {0, 0, 0, 0};
        *(ushort4*)&xb[idx] = z;
        *(ushort4*)&xb[idx + 4] = z;
    }
}

// ---------------- W1 cast+transpose: W1[512,256] fp32 -> W1t[256,512] bf16 ---
__global__ __launch_bounds__(256) void w1t_kernel(const float* __restrict__ W1,
                                                  unsigned short* __restrict__ W1t) {
    const int idx = blockIdx.x * 256 + threadIdx.x;
    const int k = idx >> 8;          // 0..511
    const int n = idx & 255;         // 0..255
    W1t[n * FIN + k] = f2bf(W1[idx]);
}

// ---------------- W2 cast+transpose: W2[256,40] fp32 -> W2t[48][256] bf16 ----
__global__ __launch_bounds__(256) void w2t_kernel(const float* __restrict__ W2,
                                                  unsigned short* __restrict__ W2t) {
    const int idx = blockIdx.x * 256 + threadIdx.x;  // 48 blocks
    const int n = idx >> 8;          // 0..47
    const int k = idx & 255;         // 0..255
    W2t[n * HD + k] = (n < NCLS) ? f2bf(W2[k * NCLS + n]) : (unsigned short)0;
}

// ---------------- GEMM1 (m97 pattern): h1 = xb @ W1t^T via global_load_lds ---
#define BM 128
#define BN 128
#define BK 32

__global__ __launch_bounds__(256) void gemm1_kernel(const unsigned short* __restrict__ xb,
                                                    const unsigned short* __restrict__ W1t,
                                                    unsigned short* __restrict__ h1) {
    __shared__ unsigned short As[BM * BK];  // 8 KB, [m][k] unpadded (DMA layout)
    __shared__ unsigned short Bs[BN * BK];  // 8 KB, [n][k]
    const int tid = threadIdx.x;
    const int wave = tid >> 6;
    const int lane = tid & 63;
    const int wm = wave >> 1;
    const int wn = wave & 1;
    const int quad = lane >> 4;
    const int col = lane & 15;
    const int m0 = blockIdx.x * BM;
    const int n0 = blockIdx.y * BN;
    const int srow = wave * 32 + (lane >> 2);
    const int skk = (lane & 3) * 8;

    f32x4 acc[4][4] = {};

    for (int k0 = 0; k0 < FIN; k0 += BK) {
        #pragma unroll
        for (int c = 0; c < 2; ++c) {
            const int r = srow + c * 16;
            gload_lds16(&xb[(size_t)(m0 + r) * FIN + k0 + skk], &As[r * BK + skk]);
            gload_lds16(&W1t[(size_t)(n0 + r) * FIN + k0 + skk], &Bs[r * BK + skk]);
        }
        __syncthreads();

        short8 af[4], bf[4];
        #pragma unroll
        for (int i = 0; i < 4; ++i)
            af[i] = *(const short8*)&As[(wm * 64 + i * 16 + col) * BK + quad * 8];
        #pragma unroll
        for (int j = 0; j < 4; ++j)
            bf[j] = *(const short8*)&Bs[(wn * 64 + j * 16 + col) * BK + quad * 8];
        #pragma unroll
        for (int i = 0; i < 4; ++i)
            #pragma unroll
            for (int j = 0; j < 4; ++j)
                acc[i][j] = __builtin_amdgcn_mfma_f32_16x16x32_bf16(af[i], bf[j], acc[i][j], 0, 0, 0);
        __syncthreads();
    }

    #pragma unroll
    for (int i = 0; i < 4; ++i) {
        #pragma unroll
        for (int reg = 0; reg < 4; ++reg) {
            const int gm = m0 + wm * 64 + i * 16 + quad * 4 + reg;
            if (gm < NNODES) {
                #pragma unroll
                for (int j = 0; j < 4; ++j) {
                    const int gc = n0 + wn * 64 + j * 16 + col;
                    h1[(size_t)gm * HD + gc] = f2bf(acc[i][j][reg]);
                }
            }
        }
    }
}

// ---------------- per-node attention scores for layer 1 ----------------------
__global__ __launch_bounds__(256) void al1_kernel(const unsigned short* __restrict__ h1,
                                                  const float* __restrict__ a_src,
                                                  const float* __restrict__ a_dst,
                                                  float* __restrict__ al_s,
                                                  float* __restrict__ al_d) {
    const int node = (blockIdx.x * 256 + threadIdx.x) >> 6;
    const int lane = threadIdx.x & 63;
    const ushort4 hb = *(const ushort4*)&h1[(size_t)node * HD + lane * 4];
    const float4 sv = *(const float4*)&a_src[lane * 4];
    const float4 dv = *(const float4*)&a_dst[lane * 4];
    const float h0 = bf2f(hb.x), h1v = bf2f(hb.y), h2v = bf2f(hb.z), h3 = bf2f(hb.w);
    float ps = h0 * sv.x + h1v * sv.y + h2v * sv.z + h3 * sv.w;
    float pd = h0 * dv.x + h1v * dv.y + h2v * dv.z + h3 * dv.w;
    #pragma unroll
    for (int off = 1; off < 16; off <<= 1) {
        ps += __shfl_xor(ps, off);
        pd += __shfl_xor(pd, off);
    }
    if ((lane & 15) == 0) {
        al_s[node * HEADS + (lane >> 4)] = ps;
        al_d[node * HEADS + (lane >> 4)] = pd;
    }
}

// ---------------- CSR build --------------------------------------------------
__global__ void deg_kernel(const int* __restrict__ ei, int E, int* __restrict__ deg) {
    const int e = blockIdx.x * 256 + threadIdx.x;
    if (e < E) atomicAdd(&deg[ei[E + e]], 1);
}

// hierarchical exclusive scan over deg[50000] (replaces 77us single-block scan)
__global__ __launch_bounds__(SBLK) void scan1_kernel(const int* __restrict__ deg,
                                                     int* __restrict__ psum,
                                                     int* __restrict__ bsum) {
    __shared__ int ws[4];
    const int t = threadIdx.x;
    const int idx = blockIdx.x * SBLK + t;
    const int lane = t & 63;
    const int w = t >> 6;
    int sv = (idx < NNODES) ? deg[idx] : 0;
    #pragma unroll
    for (int off = 1; off < 64; off <<= 1) {
        const int n = __shfl_up(sv, off);
        if (lane >= off) sv += n;
    }
    if (lane == 63) ws[w] = sv;
    __syncthreads();
    int add = 0;
    for (int i = 0; i < w; ++i) add += ws[i];
    sv += add;
    if (idx < NNODES) psum[idx] = sv;          // inclusive within block
    if (t == SBLK - 1) bsum[blockIdx.x] = sv;  // block total
}

__global__ __launch_bounds__(SBLK) void scan2_kernel(int* __restrict__ bsum,
                                                     int* __restrict__ offsets) {
    __shared__ int ws[4];
    const int t = threadIdx.x;
    const int lane = t & 63;
    const int w = t >> 6;
    int sv = (t < NSCAN) ? bsum[t] : 0;
    #pragma unroll
    for (int off = 1; off < 64; off <<= 1) {
        const int n = __shfl_up(sv, off);
        if (lane >= off) sv += n;
    }
    if (lane == 63) ws[w] = sv;
    __syncthreads();
    int add = 0;
    for (int i = 0; i < w; ++i) add += ws[i];
    sv += add;
    if (t < NSCAN) bsum[t] = sv;               // inclusive block prefix
    if (t == SBLK - 1) offsets[NNODES] = sv;   // grand total = E
}

__global__ __launch_bounds__(SBLK) void scan3_kernel(const int* __restrict__ deg,
                                                     const int* __restrict__ psum,
                                                     const int* __restrict__ bsum,
                                                     int* __restrict__ offsets) {
    const int b = blockIdx.x;
    const int idx = b * SBLK + threadIdx.x;
    if (idx < NNODES) {
        const int boff = (b > 0) ? bsum[b - 1] : 0;
        offsets[idx] = psum[idx] - deg[idx] + boff;   // exclusive prefix
    }
}

__global__ void scatter_kernel(const int* __restrict__ ei, int E,
                               const int* __restrict__ offsets,
                               int* __restrict__ cursor,
                               int* __restrict__ csr_src) {
    const int e = blockIdx.x * 256 + threadIdx.x;
    if (e < E) {
        const int dst = ei[E + e];
        const int src = ei[e];
        const int pos = offsets[dst] + atomicAdd(&cursor[dst], 1);
        csr_src[pos] = src;
    }
}

// ---------------- layer-1 aggregation: half-wave-per-edge, dual-stream -------
// Lane = (half, fl): half-wave 0 processes edge i, half-wave 1 edge i+1.
// Each lane loads a 16B ushort8 chunk (32 lanes x 16B = full 512B row).
// Direct exp (scores bounded ~|8|), -inf padding = exact no-op.
__global__ __launch_bounds__(256) void agg1_kernel(const unsigned short* __restrict__ h1,
                                                   const float* __restrict__ al_s,
                                                   const float* __restrict__ al_d,
                                                   const int* __restrict__ offsets,
                                                   const int* __restrict__ csr_src,
                                                   const float* __restrict__ b1,
                                                   unsigned short* __restrict__ h_act) {
    const int node = (blockIdx.x * 256 + threadIdx.x) >> 6;
    const int lane = threadIdx.x & 63;
    const int half = lane >> 5;
    const int fl = lane & 31;        // 16B chunk index (8 bf16 features)
    const int h = fl >> 3;           // head for features fl*8..fl*8+7
    const float ad = al_d[node * HEADS + h];
    const int start = offsets[node];
    const int end = offsets[node + 1];   // >= start+1 (self-loop)
    const int last = end - 1;

    float s = 0.f;
    float acc[8] = {};

    {
        const int idx = start + half;
        const int src = csr_src[min(idx, last)];
        float sc = (idx < end) ? al_s[src * HEADS + h] : -__builtin_inff();
        short8 v = *(const short8*)&h1[(size_t)src * HD + fl * 8];

        for (int i = start; i < end; i += 2) {
            const int j = i + 2 + half;
            const int nsrc = csr_src[min(j, last)];
            const float nsc = (j < end) ? al_s[nsrc * HEADS + h] : -__builtin_inff();
            const short8 nv = *(const short8*)&h1[(size_t)nsrc * HD + fl * 8];
            float e_ = sc + ad;
            e_ = e_ > 0.f ? e_ : NEG_SLOPE * e_;
            const float p = __expf(e_);
            s += p;
            #pragma unroll
            for (int k = 0; k < 8; ++k)
                acc[k] = fmaf(p, bf2f((unsigned short)v[k]), acc[k]);
            sc = nsc; v = nv;
        }
    }
    s += __shfl_xor(s, 32);
    #pragma unroll
    for (int k = 0; k < 8; ++k) acc[k] += __shfl_xor(acc[k], 32);

    if (half == 0) {
        const float inv = 1.f / (s + 1e-16f);
        const float4 b0 = *(const float4*)&b1[fl * 8];
        const float4 b4 = *(const float4*)&b1[fl * 8 + 4];
        float o[8];
        o[0] = acc[0] * inv + b0.x; o[1] = acc[1] * inv + b0.y;
        o[2] = acc[2] * inv + b0.z; o[3] = acc[3] * inv + b0.w;
        o[4] = acc[4] * inv + b4.x; o[5] = acc[5] * inv + b4.y;
        o[6] = acc[6] * inv + b4.z; o[7] = acc[7] * inv + b4.w;
        short8 ob;
        #pragma unroll
        for (int k = 0; k < 8; ++k) {
            const float e = o[k] > 0.f ? o[k] : expm1f(o[k]);
            ob[k] = (short)f2bf(e);
        }
        *(short8*)&h_act[(size_t)node * HD + fl * 8] = ob;
    }
}

// ---------------- GEMM2 via MFMA: h2[N,40] = h_act[N,256] @ W2 + score dots --
#define G2M 64          // nodes per block (16 per wave)
#define BSTRIDE 264

__global__ __launch_bounds__(256) void gemm2_kernel(const unsigned short* __restrict__ h_act,
                                                    const unsigned short* __restrict__ W2t,
                                                    const float* __restrict__ a_s2,
                                                    const float* __restrict__ a_d2,
                                                    unsigned short* __restrict__ h2,
                                                    float* __restrict__ al_s,
                                                    float* __restrict__ al_d) {
    __shared__ unsigned short Bt[NCLSP][BSTRIDE];  // 25.3 KB
    const int tid = threadIdx.x;
    const int wave = tid >> 6;
    const int lane = tid & 63;
    const int quad = lane >> 4;
    const int col = lane & 15;
    const int m0 = blockIdx.x * G2M;

    #pragma unroll
    for (int it = 0; it < 6; ++it) {
        const int ch = it * 256 + tid;        // 0..1535
        const int n = ch >> 5;
        const int c8 = (ch & 31) * 8;
        *(uint4*)&Bt[n][c8] = *(const uint4*)&W2t[(size_t)n * HD + c8];
    }

    const int rowm = m0 + wave * 16 + col;
    const int arow = min(rowm, NNODES - 1);
    short8 af[8];
    #pragma unroll
    for (int ks = 0; ks < 8; ++ks)
        af[ks] = *(const short8*)&h_act[(size_t)arow * HD + ks * 32 + quad * 8];

    __syncthreads();

    f32x4 acc[3] = {};
    #pragma unroll
    for (int j = 0; j < 3; ++j) {
        #pragma unroll
        for (int ks = 0; ks < 8; ++ks) {
            const short8 bfr = *(const short8*)&Bt[j * 16 + col][ks * 32 + quad * 8];
            acc[j] = __builtin_amdgcn_mfma_f32_16x16x32_bf16(af[ks], bfr, acc[j], 0, 0, 0);
        }
    }

    float ps[4] = {0.f, 0.f, 0.f, 0.f};
    float pd[4] = {0.f, 0.f, 0.f, 0.f};
    #pragma unroll
    for (int j = 0; j < 3; ++j) {
        const int c = j * 16 + col;
        const bool cv = c < NCLS;
        const float asc = cv ? a_s2[c] : 0.f;
        const float adc = cv ? a_d2[c] : 0.f;
        #pragma unroll
        for (int reg = 0; reg < 4; ++reg) {
            const float v = acc[j][reg];
            ps[reg] += v * asc;
            pd[reg] += v * adc;
            const int node = m0 + wave * 16 + quad * 4 + reg;
            if (cv && node < NNODES)
                h2[(size_t)node * NCLS + c] = f2bf(v);
        }
    }
    #pragma unroll
    for (int reg = 0; reg < 4; ++reg) {
        #pragma unroll
        for (int off = 1; off < 16; off <<= 1) {
            ps[reg] += __shfl_xor(ps[reg], off);
            pd[reg] += __shfl_xor(pd[reg], off);
        }
    }
    if (col == 0) {
        #pragma unroll
        for (int reg = 0; reg < 4; ++reg) {
            const int node = m0 + wave * 16 + quad * 4 + reg;
            if (node < NNODES) {
                al_s[node] = ps[reg];
                al_d[node] = pd[reg];
            }
        }
    }
}

// ---------------- layer-2 aggregation: dual-stream, direct exp + log_softmax -
__global__ __launch_bounds__(256) void agg2_kernel(const unsigned short* __restrict__ h2,
                                                   const float* __restrict__ al_s,
                                                   const float* __restrict__ al_d,
                                                   const int* __restrict__ offsets,
                                                   const int* __restrict__ csr_src,
                                                   const float* __restrict__ b2,
                                                   float* __restrict__ out) {
    const int node = (blockIdx.x * 256 + threadIdx.x) >> 6;
    const int lane = threadIdx.x & 63;
    const int c = lane < NCLS ? lane : NCLS - 1;
    const float ad = al_d[node];
    const int start = offsets[node];
    const int end = offsets[node + 1];
    const int last = end - 1;

    float sA = 0.f, sB = 0.f, aA = 0.f, aB = 0.f;

#define PROC2(sc_, v_, s_, a_)                            \
    {                                                     \
        float e_ = sc_ + ad;                              \
        e_ = e_ > 0.f ? e_ : NEG_SLOPE * e_;              \
        const float p_ = __expf(e_);                      \
        s_ += p_;                                         \
        a_ = fmaf(p_, v_, a_);                            \
    }

    int srcA = csr_src[start];
    int srcB = csr_src[min(start + 1, last)];
    float scA = al_s[srcA];
    float scB = (start + 1 < end) ? al_s[srcB] : -__builtin_inff();
    float vA = bf2f(h2[(size_t)srcA * NCLS + c]);
    float vB = bf2f(h2[(size_t)srcB * NCLS + c]);

    for (int i = start; i < end; i += 2) {
        const int j = i + 2;
        const int nsrcA = csr_src[min(j, last)];
        const int nsrcB = csr_src[min(j + 1, last)];
        const float nscA = (j < end) ? al_s[nsrcA] : -__builtin_inff();
        const float nscB = (j + 1 < end) ? al_s[nsrcB] : -__builtin_inff();
        const float nvA = bf2f(h2[(size_t)nsrcA * NCLS + c]);
        const float nvB = bf2f(h2[(size_t)nsrcB * NCLS + c]);
        PROC2(scA, vA, sA, aA);
        PROC2(scB, vB, sB, aB);
        scA = nscA; vA = nvA; scB = nscB; vB = nvB;
    }
    const float s = sA + sB;
    const float acc = aA + aB;
#undef PROC2

    float o = acc / (s + 1e-16f) + b2[c];
    float mx = (lane < NCLS) ? o : -1e30f;
    #pragma unroll
    for (int off = 1; off < 64; off <<= 1) mx = fmaxf(mx, __shfl_xor(mx, off));
    float ex = (lane < NCLS) ? __expf(o - mx) : 0.f;
    #pragma unroll
    for (int off = 1; off < 64; off <<= 1) ex += __shfl_xor(ex, off);
    const float res = o - mx - logf(ex);
    if (lane < NCLS) out[(size_t)node * NCLS + lane] = res;
}

// ---------------- launch -----------------------------------------------------
extern "C" void kernel_launch(void* const* d_in, const int* in_sizes, int n_in,
                              void* d_out, int out_size, void* d_ws, size_t ws_size,
                              hipStream_t stream) {
    const float* x      = (const float*)d_in[0];
    const int*   ei     = (const int*)d_in[1];
    const float* W1     = (const float*)d_in[2];
    const float* a_src1 = (const float*)d_in[3];
    const float* a_dst1 = (const float*)d_in[4];
    const float* b1     = (const float*)d_in[5];
    const float* W2     = (const float*)d_in[6];
    const float* a_src2 = (const float*)d_in[7];
    const float* a_dst2 = (const float*)d_in[8];
    const float* b2     = (const float*)d_in[9];
    float* out = (float*)d_out;
    const int E = in_sizes[1] / 2;

    char* ws = (char*)d_ws;
    size_t off = 0;
    auto alloc = [&](size_t bytes) -> char* {
        char* p = ws + off;
        off += (bytes + 255) & ~(size_t)255;
        return p;
    };
    unsigned short* xb    = (unsigned short*)alloc((size_t)NPAD * FIN * 2);
    unsigned short* W1t   = (unsigned short*)alloc((size_t)FIN * HD * 2);
    unsigned short* W2t   = (unsigned short*)alloc((size_t)NCLSP * HD * 2);
    unsigned short* h1    = (unsigned short*)alloc((size_t)NNODES * HD * 2);
    unsigned short* h_act = (unsigned short*)alloc((size_t)NNODES * HD * 2);
    unsigned short* h2    = (unsigned short*)alloc((size_t)NNODES * NCLS * 2);
    float* al_s1  = (float*)alloc((size_t)NNODES * HEADS * 4);
    float* al_d1  = (float*)alloc((size_t)NNODES * HEADS * 4);
    float* al_s2  = (float*)alloc((size_t)NNODES * 4);
    float* al_d2  = (float*)alloc((size_t)NNODES * 4);
    int*   deg    = (int*)alloc((size_t)NNODES * 4);
    int*   psum   = (int*)alloc((size_t)NNODES * 4);
    int*   bsum   = (int*)alloc((size_t)SBLK * 4);
    int*   offs   = (int*)alloc((size_t)(NNODES + 1) * 4);
    int*   cursor = (int*)alloc((size_t)NNODES * 4);
    int*   csrsrc = (int*)alloc((size_t)E * 4);

    hipMemsetAsync(deg, 0, (size_t)NNODES * 4, stream);
    hipMemsetAsync(cursor, 0, (size_t)NNODES * 4, stream);

    const int eb = (E + 255) / 256;
    xcast_kernel<<<(int)((size_t)NPAD * FIN / 8 / 256), 256, 0, stream>>>(x, xb);
    w1t_kernel<<<FIN * HD / 256, 256, 0, stream>>>(W1, W1t);
    w2t_kernel<<<NCLSP, 256, 0, stream>>>(W2, W2t);
    deg_kernel<<<eb, 256, 0, stream>>>(ei, E, deg);
    scan1_kernel<<<NSCAN, SBLK, 0, stream>>>(deg, psum, bsum);
    scan2_kernel<<<1, SBLK, 0, stream>>>(bsum, offs);
    scan3_kernel<<<NSCAN, SBLK, 0, stream>>>(deg, psum, bsum, offs);
    scatter_kernel<<<eb, 256, 0, stream>>>(ei, E, offs, cursor, csrsrc);

    gemm1_kernel<<<dim3((NNODES + BM - 1) / BM, HD / BN), 256, 0, stream>>>(xb, W1t, h1);
    al1_kernel<<<NNODES / 4, 256, 0, stream>>>(h1, a_src1, a_dst1, al_s1, al_d1);
    agg1_kernel<<<NNODES / 4, 256, 0, stream>>>(h1, al_s1, al_d1, offs, csrsrc, b1, h_act);
    gemm2_kernel<<<(NNODES + G2M - 1) / G2M, 256, 0, stream>>>(h_act, W2t, a_src2, a_dst2, h2, al_s2, al_d2);
    agg2_kernel<<<NNODES / 4, 256, 0, stream>>>(h2, al_s2, al_d2, offs, csrsrc, b2, out);
}

// Round 14
// 449.716 us; speedup vs baseline: 1.2433x; 1.0014x over previous
//
#include <hip/hip_runtime.h>
#include <math.h>

#define NNODES 50000
#define NPAD 50176         // padded rows for unguarded global_load_lds staging
#define FIN 512
#define HID 64
#define HEADS 4
#define HD (HEADS * HID)   // 256
#define NCLS 40
#define NCLSP 48           // padded to 3x16 for MFMA n-tiles
#define NEG_SLOPE 0.2f
#define SBLK 256
#define NSCAN ((NNODES + SBLK - 1) / SBLK)   // 196

typedef __attribute__((ext_vector_type(8))) short short8;
typedef __attribute__((ext_vector_type(4))) float f32x4;

static __device__ inline unsigned short f2bf(float f) {
    unsigned int u = __builtin_bit_cast(unsigned int, f);
    unsigned int r = (u + 0x7FFFu + ((u >> 16) & 1u)) >> 16;
    return (unsigned short)r;
}
static __device__ inline float bf2f(unsigned short b) {
    return __builtin_bit_cast(float, (unsigned int)b << 16);
}
static __device__ inline void gload_lds16(const unsigned short* g, unsigned short* l) {
    __builtin_amdgcn_global_load_lds(
        (const __attribute__((address_space(1))) unsigned int*)g,
        (__attribute__((address_space(3))) unsigned int*)l, 16, 0, 0);
}

// ---------------- x cast: x[50000,512] fp32 -> xb[50176,512] bf16 (pad=0) ----
__global__ __launch_bounds__(256) void xcast_kernel(const float* __restrict__ x,
                                                    unsigned short* __restrict__ xb) {
    const size_t idx = ((size_t)blockIdx.x * 256 + threadIdx.x) * 8;
    if (idx < (size_t)NNODES * FIN) {
        const float4 v0 = *(const float4*)&x[idx];
        const float4 v1 = *(const float4*)&x[idx + 4];
        ushort4 p0, p1;
        p0.x = f2bf(v0.x); p0.y = f2bf(v0.y); p0.z = f2bf(v0.z); p0.w = f2bf(v0.w);
        p1.x = f2bf(v1.x); p1.y = f2bf(v1.y); p1.z = f2bf(v1.z); p1.w = f2bf(v1.w);
        *(ushort4*)&xb[idx] = p0;
        *(ushort4*)&xb[idx + 4] = p1;
    } else {
        const ushort4 z = {0, 0, 0, 0};
        *(ushort4*)&xb[idx] = z;
        *(ushort4*)&xb[idx + 4] = z;
    }
}

// ---------------- W1 cast+transpose: W1[512,256] fp32 -> W1t[256,512] bf16 ---
__global__ __launch_bounds__(256) void w1t_kernel(const float* __restrict__ W1,
                                                  unsigned short* __restrict__ W1t) {
    const int idx = blockIdx.x * 256 + threadIdx.x;
    const int k = idx >> 8;          // 0..511
    const int n = idx & 255;         // 0..255
    W1t[n * FIN + k] = f2bf(W1[idx]);
}

// ---------------- W2 cast+transpose: W2[256,40] fp32 -> W2t[48][256] bf16 ----
__global__ __launch_bounds__(256) void w2t_kernel(const float* __restrict__ W2,
                                                  unsigned short* __restrict__ W2t) {
    const int idx = blockIdx.x * 256 + threadIdx.x;  // 48 blocks
    const int n = idx >> 8;          // 0..47
    const int k = idx & 255;         // 0..255
    W2t[n * HD + k] = (n < NCLS) ? f2bf(W2[k * NCLS + n]) : (unsigned short)0;
}

// ---------------- GEMM1 v2: BM=64, BN=256 (full-width rows) + fused al1 ------
// xb read exactly once (no y-split); W1t (256KB) is L2-resident. Wave w's
// 64-col slice == head w, so per-head score dots complete within-wave.
#define BM 64
#define BN 256
#define BK 32

__global__ __launch_bounds__(256) void gemm1_kernel(const unsigned short* __restrict__ xb,
                                                    const unsigned short* __restrict__ W1t,
                                                    const float* __restrict__ a_src,
                                                    const float* __restrict__ a_dst,
                                                    unsigned short* __restrict__ h1,
                                                    float* __restrict__ al_s,
                                                    float* __restrict__ al_d) {
    __shared__ unsigned short As[BM * BK];  // 4 KB  [m][k] (DMA layout)
    __shared__ unsigned short Bs[BN * BK];  // 16 KB [n][k]
    const int tid = threadIdx.x;
    const int wave = tid >> 6;
    const int lane = tid & 63;
    const int quad = lane >> 4;
    const int col = lane & 15;
    const int m0 = blockIdx.x * BM;
    // staging: wave-uniform LDS base + lane*16B; lane covers 4-lanes-per-row
    const int srow = lane >> 2;          // 0..15 within a 16-row group
    const int skk = (lane & 3) * 8;      // 8-elem (16B) k-chunk

    f32x4 acc[4][4] = {};

    for (int k0 = 0; k0 < FIN; k0 += BK) {
        // A: 64 rows x 32k = 4KB = 256 lanes x 16B (one DMA per thread)
        {
            const int r = wave * 16 + srow;
            gload_lds16(&xb[(size_t)(m0 + r) * FIN + k0 + skk], &As[r * BK + skk]);
        }
        // B: 256 rows x 32k = 16KB (four DMAs per thread)
        #pragma unroll
        for (int c = 0; c < 4; ++c) {
            const int r = c * 64 + wave * 16 + srow;
            gload_lds16(&W1t[(size_t)r * FIN + k0 + skk], &Bs[r * BK + skk]);
        }
        __syncthreads();

        short8 af[4], bf[4];
        #pragma unroll
        for (int i = 0; i < 4; ++i)
            af[i] = *(const short8*)&As[(i * 16 + col) * BK + quad * 8];
        #pragma unroll
        for (int j = 0; j < 4; ++j)
            bf[j] = *(const short8*)&Bs[(wave * 64 + j * 16 + col) * BK + quad * 8];
        #pragma unroll
        for (int i = 0; i < 4; ++i)
            #pragma unroll
            for (int j = 0; j < 4; ++j)
                acc[i][j] = __builtin_amdgcn_mfma_f32_16x16x32_bf16(af[i], bf[j], acc[i][j], 0, 0, 0);
        __syncthreads();
    }

    // epilogue: D row = quad*4 + reg (within i*16 tile), col c = wave*64+j*16+col
    // h1 write + fused per-head attention score dots (head == wave)
    float asv[4], adv[4];
    #pragma unroll
    for (int j = 0; j < 4; ++j) {
        asv[j] = a_src[wave * 64 + j * 16 + col];
        adv[j] = a_dst[wave * 64 + j * 16 + col];
    }
    #pragma unroll
    for (int i = 0; i < 4; ++i) {
        #pragma unroll
        for (int reg = 0; reg < 4; ++reg) {
            const int row = i * 16 + quad * 4 + reg;
            const int gm = m0 + row;
            float ds = 0.f, dd = 0.f;
            #pragma unroll
            for (int j = 0; j < 4; ++j) {
                const float v = acc[i][j][reg];
                ds = fmaf(v, asv[j], ds);
                dd = fmaf(v, adv[j], dd);
                if (gm < NNODES) {
                    const int gc = wave * 64 + j * 16 + col;
                    h1[(size_t)gm * HD + gc] = f2bf(v);
                }
            }
            // reduce over the 16 col-lanes (same quad group)
            #pragma unroll
            for (int off = 1; off < 16; off <<= 1) {
                ds += __shfl_xor(ds, off);
                dd += __shfl_xor(dd, off);
            }
            if (col == 0 && gm < NNODES) {
                al_s[gm * HEADS + wave] = ds;
                al_d[gm * HEADS + wave] = dd;
            }
        }
    }
}

// ---------------- CSR build --------------------------------------------------
__global__ void deg_kernel(const int* __restrict__ ei, int E, int* __restrict__ deg) {
    const int e = blockIdx.x * 256 + threadIdx.x;
    if (e < E) atomicAdd(&deg[ei[E + e]], 1);
}

// hierarchical exclusive scan over deg[50000]
__global__ __launch_bounds__(SBLK) void scan1_kernel(const int* __restrict__ deg,
                                                     int* __restrict__ psum,
                                                     int* __restrict__ bsum) {
    __shared__ int ws[4];
    const int t = threadIdx.x;
    const int idx = blockIdx.x * SBLK + t;
    const int lane = t & 63;
    const int w = t >> 6;
    int sv = (idx < NNODES) ? deg[idx] : 0;
    #pragma unroll
    for (int off = 1; off < 64; off <<= 1) {
        const int n = __shfl_up(sv, off);
        if (lane >= off) sv += n;
    }
    if (lane == 63) ws[w] = sv;
    __syncthreads();
    int add = 0;
    for (int i = 0; i < w; ++i) add += ws[i];
    sv += add;
    if (idx < NNODES) psum[idx] = sv;
    if (t == SBLK - 1) bsum[blockIdx.x] = sv;
}

__global__ __launch_bounds__(SBLK) void scan2_kernel(int* __restrict__ bsum,
                                                     int* __restrict__ offsets) {
    __shared__ int ws[4];
    const int t = threadIdx.x;
    const int lane = t & 63;
    const int w = t >> 6;
    int sv = (t < NSCAN) ? bsum[t] : 0;
    #pragma unroll
    for (int off = 1; off < 64; off <<= 1) {
        const int n = __shfl_up(sv, off);
        if (lane >= off) sv += n;
    }
    if (lane == 63) ws[w] = sv;
    __syncthreads();
    int add = 0;
    for (int i = 0; i < w; ++i) add += ws[i];
    sv += add;
    if (t < NSCAN) bsum[t] = sv;
    if (t == SBLK - 1) offsets[NNODES] = sv;
}

__global__ __launch_bounds__(SBLK) void scan3_kernel(const int* __restrict__ deg,
                                                     const int* __restrict__ psum,
                                                     const int* __restrict__ bsum,
                                                     int* __restrict__ offsets) {
    const int b = blockIdx.x;
    const int idx = b * SBLK + threadIdx.x;
    if (idx < NNODES) {
        const int boff = (b > 0) ? bsum[b - 1] : 0;
        offsets[idx] = psum[idx] - deg[idx] + boff;
    }
}

__global__ void scatter_kernel(const int* __restrict__ ei, int E,
                               const int* __restrict__ offsets,
                               int* __restrict__ cursor,
                               int* __restrict__ csr_src) {
    const int e = blockIdx.x * 256 + threadIdx.x;
    if (e < E) {
        const int dst = ei[E + e];
        const int src = ei[e];
        const int pos = offsets[dst] + atomicAdd(&cursor[dst], 1);
        csr_src[pos] = src;
    }
}

// ---------------- layer-1 aggregation: half-wave-per-edge, dual-stream -------
__global__ __launch_bounds__(256) void agg1_kernel(const unsigned short* __restrict__ h1,
                                                   const float* __restrict__ al_s,
                                                   const float* __restrict__ al_d,
                                                   const int* __restrict__ offsets,
                                                   const int* __restrict__ csr_src,
                                                   const float* __restrict__ b1,
                                                   unsigned short* __restrict__ h_act) {
    const int node = (blockIdx.x * 256 + threadIdx.x) >> 6;
    const int lane = threadIdx.x & 63;
    const int half = lane >> 5;
    const int fl = lane & 31;        // 16B chunk index (8 bf16 features)
    const int h = fl >> 3;           // head for features fl*8..fl*8+7
    const float ad = al_d[node * HEADS + h];
    const int start = offsets[node];
    const int end = offsets[node + 1];
    const int last = end - 1;

    float s = 0.f;
    float acc[8] = {};

    {
        const int idx = start + half;
        const int src = csr_src[min(idx, last)];
        float sc = (idx < end) ? al_s[src * HEADS + h] : -__builtin_inff();
        short8 v = *(const short8*)&h1[(size_t)src * HD + fl * 8];

        for (int i = start; i < end; i += 2) {
            const int j = i + 2 + half;
            const int nsrc = csr_src[min(j, last)];
            const float nsc = (j < end) ? al_s[nsrc * HEADS + h] : -__builtin_inff();
            const short8 nv = *(const short8*)&h1[(size_t)nsrc * HD + fl * 8];
            float e_ = sc + ad;
            e_ = e_ > 0.f ? e_ : NEG_SLOPE * e_;
            const float p = __expf(e_);
            s += p;
            #pragma unroll
            for (int k = 0; k < 8; ++k)
                acc[k] = fmaf(p, bf2f((unsigned short)v[k]), acc[k]);
            sc = nsc; v = nv;
        }
    }
    s += __shfl_xor(s, 32);
    #pragma unroll
    for (int k = 0; k < 8; ++k) acc[k] += __shfl_xor(acc[k], 32);

    if (half == 0) {
        const float inv = 1.f / (s + 1e-16f);
        const float4 b0 = *(const float4*)&b1[fl * 8];
        const float4 b4 = *(const float4*)&b1[fl * 8 + 4];
        float o[8];
        o[0] = acc[0] * inv + b0.x; o[1] = acc[1] * inv + b0.y;
        o[2] = acc[2] * inv + b0.z; o[3] = acc[3] * inv + b0.w;
        o[4] = acc[4] * inv + b4.x; o[5] = acc[5] * inv + b4.y;
        o[6] = acc[6] * inv + b4.z; o[7] = acc[7] * inv + b4.w;
        short8 ob;
        #pragma unroll
        for (int k = 0; k < 8; ++k) {
            const float e = o[k] > 0.f ? o[k] : expm1f(o[k]);
            ob[k] = (short)f2bf(e);
        }
        *(short8*)&h_act[(size_t)node * HD + fl * 8] = ob;
    }
}

// ---------------- GEMM2 via MFMA: h2[N,40] = h_act[N,256] @ W2 + score dots --
#define G2M 64          // nodes per block (16 per wave)
#define BSTRIDE 264

__global__ __launch_bounds__(256) void gemm2_kernel(const unsigned short* __restrict__ h_act,
                                                    const unsigned short* __restrict__ W2t,
                                                    const float* __restrict__ a_s2,
                                                    const float* __restrict__ a_d2,
                                                    unsigned short* __restrict__ h2,
                                                    float* __restrict__ al_s,
                                                    float* __restrict__ al_d) {
    __shared__ unsigned short Bt[NCLSP][BSTRIDE];  // 25.3 KB
    const int tid = threadIdx.x;
    const int wave = tid >> 6;
    const int lane = tid & 63;
    const int quad = lane >> 4;
    const int col = lane & 15;
    const int m0 = blockIdx.x * G2M;

    #pragma unroll
    for (int it = 0; it < 6; ++it) {
        const int ch = it * 256 + tid;        // 0..1535
        const int n = ch >> 5;
        const int c8 = (ch & 31) * 8;
        *(uint4*)&Bt[n][c8] = *(const uint4*)&W2t[(size_t)n * HD + c8];
    }

    const int rowm = m0 + wave * 16 + col;
    const int arow = min(rowm, NNODES - 1);
    short8 af[8];
    #pragma unroll
    for (int ks = 0; ks < 8; ++ks)
        af[ks] = *(const short8*)&h_act[(size_t)arow * HD + ks * 32 + quad * 8];

    __syncthreads();

    f32x4 acc[3] = {};
    #pragma unroll
    for (int j = 0; j < 3; ++j) {
        #pragma unroll
        for (int ks = 0; ks < 8; ++ks) {
            const short8 bfr = *(const short8*)&Bt[j * 16 + col][ks * 32 + quad * 8];
            acc[j] = __builtin_amdgcn_mfma_f32_16x16x32_bf16(af[ks], bfr, acc[j], 0, 0, 0);
        }
    }

    float ps[4] = {0.f, 0.f, 0.f, 0.f};
    float pd[4] = {0.f, 0.f, 0.f, 0.f};
    #pragma unroll
    for (int j = 0; j < 3; ++j) {
        const int c = j * 16 + col;
        const bool cv = c < NCLS;
        const float asc = cv ? a_s2[c] : 0.f;
        const float adc = cv ? a_d2[c] : 0.f;
        #pragma unroll
        for (int reg = 0; reg < 4; ++reg) {
            const float v = acc[j][reg];
            ps[reg] += v * asc;
            pd[reg] += v * adc;
            const int node = m0 + wave * 16 + quad * 4 + reg;
            if (cv && node < NNODES)
                h2[(size_t)node * NCLS + c] = f2bf(v);
        }
    }
    #pragma unroll
    for (int reg = 0; reg < 4; ++reg) {
        #pragma unroll
        for (int off = 1; off < 16; off <<= 1) {
            ps[reg] += __shfl_xor(ps[reg], off);
            pd[reg] += __shfl_xor(pd[reg], off);
        }
    }
    if (col == 0) {
        #pragma unroll
        for (int reg = 0; reg < 4; ++reg) {
            const int node = m0 + wave * 16 + quad * 4 + reg;
            if (node < NNODES) {
                al_s[node] = ps[reg];
                al_d[node] = pd[reg];
            }
        }
    }
}

// ---------------- layer-2 aggregation: dual-stream, direct exp + log_softmax -
__global__ __launch_bounds__(256) void agg2_kernel(const unsigned short* __restrict__ h2,
                                                   const float* __restrict__ al_s,
                                                   const float* __restrict__ al_d,
                                                   const int* __restrict__ offsets,
                                                   const int* __restrict__ csr_src,
                                                   const float* __restrict__ b2,
                                                   float* __restrict__ out) {
    const int node = (blockIdx.x * 256 + threadIdx.x) >> 6;
    const int lane = threadIdx.x & 63;
    const int c = lane < NCLS ? lane : NCLS - 1;
    const float ad = al_d[node];
    const int start = offsets[node];
    const int end = offsets[node + 1];
    const int last = end - 1;

    float sA = 0.f, sB = 0.f, aA = 0.f, aB = 0.f;

#define PROC2(sc_, v_, s_, a_)                            \
    {                                                     \
        float e_ = sc_ + ad;                              \
        e_ = e_ > 0.f ? e_ : NEG_SLOPE * e_;              \
        const float p_ = __expf(e_);                      \
        s_ += p_;                                         \
        a_ = fmaf(p_, v_, a_);                            \
    }

    int srcA = csr_src[start];
    int srcB = csr_src[min(start + 1, last)];
    float scA = al_s[srcA];
    float scB = (start + 1 < end) ? al_s[srcB] : -__builtin_inff();
    float vA = bf2f(h2[(size_t)srcA * NCLS + c]);
    float vB = bf2f(h2[(size_t)srcB * NCLS + c]);

    for (int i = start; i < end; i += 2) {
        const int j = i + 2;
        const int nsrcA = csr_src[min(j, last)];
        const int nsrcB = csr_src[min(j + 1, last)];
        const float nscA = (j < end) ? al_s[nsrcA] : -__builtin_inff();
        const float nscB = (j + 1 < end) ? al_s[nsrcB] : -__builtin_inff();
        const float nvA = bf2f(h2[(size_t)nsrcA * NCLS + c]);
        const float nvB = bf2f(h2[(size_t)nsrcB * NCLS + c]);
        PROC2(scA, vA, sA, aA);
        PROC2(scB, vB, sB, aB);
        scA = nscA; vA = nvA; scB = nscB; vB = nvB;
    }
    const float s = sA + sB;
    const float acc = aA + aB;
#undef PROC2

    float o = acc / (s + 1e-16f) + b2[c];
    float mx = (lane < NCLS) ? o : -1e30f;
    #pragma unroll
    for (int off = 1; off < 64; off <<= 1) mx = fmaxf(mx, __shfl_xor(mx, off));
    float ex = (lane < NCLS) ? __expf(o - mx) : 0.f;
    #pragma unroll
    for (int off = 1; off < 64; off <<= 1) ex += __shfl_xor(ex, off);
    const float res = o - mx - logf(ex);
    if (lane < NCLS) out[(size_t)node * NCLS + lane] = res;
}

// ---------------- launch -----------------------------------------------------
extern "C" void kernel_launch(void* const* d_in, const int* in_sizes, int n_in,
                              void* d_out, int out_size, void* d_ws, size_t ws_size,
                              hipStream_t stream) {
    const float* x      = (const float*)d_in[0];
    const int*   ei     = (const int*)d_in[1];
    const float* W1     = (const float*)d_in[2];
    const float* a_src1 = (const float*)d_in[3];
    const float* a_dst1 = (const float*)d_in[4];
    const float* b1     = (const float*)d_in[5];
    const float* W2     = (const float*)d_in[6];
    const float* a_src2 = (const float*)d_in[7];
    const float* a_dst2 = (const float*)d_in[8];
    const float* b2     = (const float*)d_in[9];
    float* out = (float*)d_out;
    const int E = in_sizes[1] / 2;

    char* ws = (char*)d_ws;
    size_t off = 0;
    auto alloc = [&](size_t bytes) -> char* {
        char* p = ws + off;
        off += (bytes + 255) & ~(size_t)255;
        return p;
    };
    unsigned short* xb    = (unsigned short*)alloc((size_t)NPAD * FIN * 2);
    unsigned short* W1t   = (unsigned short*)alloc((size_t)FIN * HD * 2);
    unsigned short* W2t   = (unsigned short*)alloc((size_t)NCLSP * HD * 2);
    unsigned short* h1    = (unsigned short*)alloc((size_t)NNODES * HD * 2);
    unsigned short* h_act = (unsigned short*)alloc((size_t)NNODES * HD * 2);
    unsigned short* h2    = (unsigned short*)alloc((size_t)NNODES * NCLS * 2);
    float* al_s1  = (float*)alloc((size_t)NNODES * HEADS * 4);
    float* al_d1  = (float*)alloc((size_t)NNODES * HEADS * 4);
    float* al_s2  = (float*)alloc((size_t)NNODES * 4);
    float* al_d2  = (float*)alloc((size_t)NNODES * 4);
    int*   deg    = (int*)alloc((size_t)NNODES * 4);
    int*   psum   = (int*)alloc((size_t)NNODES * 4);
    int*   bsum   = (int*)alloc((size_t)SBLK * 4);
    int*   offs   = (int*)alloc((size_t)(NNODES + 1) * 4);
    int*   cursor = (int*)alloc((size_t)NNODES * 4);
    int*   csrsrc = (int*)alloc((size_t)E * 4);

    hipMemsetAsync(deg, 0, (size_t)NNODES * 4, stream);
    hipMemsetAsync(cursor, 0, (size_t)NNODES * 4, stream);

    const int eb = (E + 255) / 256;
    xcast_kernel<<<(int)((size_t)NPAD * FIN / 8 / 256), 256, 0, stream>>>(x, xb);
    w1t_kernel<<<FIN * HD / 256, 256, 0, stream>>>(W1, W1t);
    w2t_kernel<<<NCLSP, 256, 0, stream>>>(W2, W2t);
    deg_kernel<<<eb, 256, 0, stream>>>(ei, E, deg);
    scan1_kernel<<<NSCAN, SBLK, 0, stream>>>(deg, psum, bsum);
    scan2_kernel<<<1, SBLK, 0, stream>>>(bsum, offs);
    scan3_kernel<<<NSCAN, SBLK, 0, stream>>>(deg, psum, bsum, offs);
    scatter_kernel<<<eb, 256, 0, stream>>>(ei, E, offs, cursor, csrsrc);

    gemm1_kernel<<<NPAD / BM, 256, 0, stream>>>(xb, W1t, a_src1, a_dst1, h1, al_s1, al_d1);
    agg1_kernel<<<NNODES / 4, 256, 0, stream>>>(h1, al_s1, al_d1, offs, csrsrc, b1, h_act);
    gemm2_kernel<<<(NNODES + G2M - 1) / G2M, 256, 0, stream>>>(h_act, W2t, a_src2, a_dst2, h2, al_s2, al_d2);
    agg2_kernel<<<NNODES / 4, 256, 0, stream>>>(h2, al_s2, al_d2, offs, csrsrc, b2, out);
}